// Round 5
// baseline (71757.550 us; speedup 1.0000x reference)
//
#include <hip/hip_runtime.h>
#include <math.h>

#define Bn 64
#define Hn 1024
#define En 512
#define Sn 512
#define NBLK 256

typedef _Float16 f16;
typedef _Float16 half8 __attribute__((ext_vector_type(8)));
typedef float f32x4 __attribute__((ext_vector_type(4)));

// ============================================================================
// Persistent-LSTM design (round 5):
//  - 256 blocks x 1024 threads, 1 block/CU, all co-resident -> device-scope
//    atomic grid barrier once per step (no per-step kernel launches).
//  - Block bb owns units [bb*4, bb*4+4) x 4 gates = 16 B-frag columns,
//    n = g*4 + du. Full K = 1536 (h:1024 + e:512) per block -> no partials.
//  - Wave wv: mt = wv&3 (batch tile), kq = wv>>2; kc = kq + 4*i (stride-4).
//    Recurrent-weight fragments (8 kc x hi/lo) pinned in VGPRs all 512 steps.
//  - c lives in a register of its cell-thread for the whole sequence.
//
// Fragment layouts (gfx950 mfma_f32_16x16x32_f16, HW-verified):
//   A[m][k]: m = lane&15, k = (lane>>4)*8 + j
//   B[k][n]: n = lane&15, k = (lane>>4)*8 + j
//   C/D[m][n]: n = lane&15, m = (lane>>4)*4 + reg
//
// hF (A-side, f16, double-buffered): [(kc*4 + mt)*64 + lane]*8+j =
//   h[b=mt*16+(lane&15)][k=kc*32+(lane>>4)*8+j], kc 0..31.
// eF (A-side, f16): [s][(kcx*4+mt)*64+lane]*8+j over e-k 0..511.
// wp (B-side, hi + lo*2048): [((bb*48 + kc)*64 + lane)*8+j] =
//   W_g[u=bb*4+du][k], n=lane&15, g=n>>2, du=n&3;
//   kc<32: Wh_g, k=kc*32+(lane>>4)*8+j; kc>=32: Wx_g, k=(kc-32)*32+...
// ============================================================================

__global__ __launch_bounds__(256) void wpack_kernel(
    const float* __restrict__ Whi_, const float* __restrict__ Whf_,
    const float* __restrict__ Whg_, const float* __restrict__ Who_,
    const float* __restrict__ Wxi_, const float* __restrict__ Wxf_,
    const float* __restrict__ Wxg_, const float* __restrict__ Wxo_,
    f16* __restrict__ wpHi, f16* __restrict__ wpLo)
{
    int t = blockIdx.x * 256 + threadIdx.x;   // 786432 = 256*48*64
    int lane = t & 63;
    int rest = t >> 6;
    int kc = rest % 48;
    int bb = rest / 48;
    int n = lane & 15, g = n >> 2, du = n & 3;
    int u = bb * 4 + du;
    int klo = (lane >> 4) << 3;
    const float* Wh = (g == 0 ? Whi_ : g == 1 ? Whf_ : g == 2 ? Whg_ : Who_);
    const float* Wx = (g == 0 ? Wxi_ : g == 1 ? Wxf_ : g == 2 ? Wxg_ : Wxo_);
    const float* src = (kc < 32) ? (Wh + (size_t)u * Hn + kc * 32 + klo)
                                 : (Wx + (size_t)u * En + (kc - 32) * 32 + klo);
    float4 v0 = ((const float4*)src)[0];
    float4 v1 = ((const float4*)src)[1];
    float w[8] = {v0.x, v0.y, v0.z, v0.w, v1.x, v1.y, v1.z, v1.w};
    #pragma unroll
    for (int j = 0; j < 8; ++j) {
        f16 hi = (f16)w[j];
        float lo = (w[j] - (float)hi) * 2048.0f;
        wpHi[(size_t)t * 8 + j] = hi;
        wpLo[(size_t)t * 8 + j] = (f16)lo;
    }
}

__global__ __launch_bounds__(256) void epack_kernel(
    const int* __restrict__ x, const float* __restrict__ emb,
    f16* __restrict__ eF)
{
    int t = blockIdx.x * 256 + threadIdx.x;   // 2097152 = 512*16*4*64
    int lane = t & 63;
    int q = t >> 6;
    int mt = q & 3; q >>= 2;
    int kc2 = q & 15;
    int s = q >> 4;
    int b = mt * 16 + (lane & 15);
    int tok = x[b * Sn + s];
    int k = kc2 * 32 + ((lane >> 4) << 3);
    const float* src = emb + (size_t)tok * En + k;
    float4 v0 = ((const float4*)src)[0];
    float4 v1 = ((const float4*)src)[1];
    f16* dst = eF + (size_t)t * 8;
    dst[0] = (f16)v0.x; dst[1] = (f16)v0.y; dst[2] = (f16)v0.z; dst[3] = (f16)v0.w;
    dst[4] = (f16)v1.x; dst[5] = (f16)v1.y; dst[6] = (f16)v1.z; dst[7] = (f16)v1.w;
}

// ---- the persistent kernel ----
__global__ __launch_bounds__(1024, 4) void lstm_persist(
    f16* __restrict__ hF,                 // 2 buffers x 65536 halves
    const half8* __restrict__ eF,
    const half8* __restrict__ wpHi, const half8* __restrict__ wpLo,
    const float* __restrict__ bi, const float* __restrict__ bf,
    const float* __restrict__ bg, const float* __restrict__ bo,
    float* __restrict__ hOut, float* __restrict__ cOut,
    int* __restrict__ barCnt)
{
    __shared__ float preW[16][256];       // per-wave D tiles, 16 KB

    const int tid  = threadIdx.x;
    const int lane = tid & 63;
    const int wv   = tid >> 6;
    const int mt   = wv & 3;
    const int kq   = wv >> 2;
    const int bb   = blockIdx.x;

    const size_t wbase = (size_t)(bb * 48) * 64 + lane;

    // pin recurrent-weight fragments in VGPRs for the whole sequence
    half8 whH[8], whL[8];
    #pragma unroll
    for (int i = 0; i < 8; ++i) {
        int kc = kq + 4 * i;
        whH[i] = wpHi[wbase + (size_t)kc * 64];
        whL[i] = wpLo[wbase + (size_t)kc * 64];
    }

    // cell-thread persistent state
    float bi_r = 0.f, bf_r = 0.f, bg_r = 0.f, bo_r = 0.f, cReg = 0.f;
    const int bcell = tid >> 2, ducell = tid & 3;
    const int colcell = bb * 4 + ducell;
    if (tid < 256) {
        bi_r = bi[colcell]; bf_r = bf[colcell];
        bg_r = bg[colcell]; bo_r = bo[colcell];
    }
    // precompute hF-scatter offset for the cell thread
    const int kch = colcell >> 5, dk = colcell & 31;
    const int lp  = ((dk >> 3) << 4) | (bcell & 15);
    const int mtp = bcell >> 4;
    const size_t hfoOff = ((size_t)((kch * 4 + mtp) * 64 + lp)) * 8 + (dk & 7);

    for (int s = 0; s < Sn; ++s) {
        const half8* hin = (const half8*)(hF + (size_t)(s & 1) * 65536) + lane;
        const half8* eFs = eF + (size_t)s * 4096 + lane;

        f32x4 accH = {0.f, 0.f, 0.f, 0.f};
        f32x4 accL = {0.f, 0.f, 0.f, 0.f};
        #pragma unroll
        for (int i = 0; i < 8; ++i) {
            int kc = kq + 4 * i;
            half8 a = hin[(size_t)((kc * 4 + mt) * 64)];
            accH = __builtin_amdgcn_mfma_f32_16x16x32_f16(a, whH[i], accH, 0, 0, 0);
            accL = __builtin_amdgcn_mfma_f32_16x16x32_f16(a, whL[i], accL, 0, 0, 0);
        }
        #pragma unroll
        for (int i = 0; i < 4; ++i) {
            int kcx = kq + 4 * i;
            half8 a  = eFs[(size_t)((kcx * 4 + mt) * 64)];
            half8 bh = wpHi[wbase + (size_t)(32 + kcx) * 64];
            half8 bl = wpLo[wbase + (size_t)(32 + kcx) * 64];
            accH = __builtin_amdgcn_mfma_f32_16x16x32_f16(a, bh, accH, 0, 0, 0);
            accL = __builtin_amdgcn_mfma_f32_16x16x32_f16(a, bl, accL, 0, 0, 0);
        }

        f32x4 v;
        #pragma unroll
        for (int r = 0; r < 4; ++r) v[r] = accH[r] + accL[r] * (1.0f / 2048.0f);
        *(f32x4*)&preW[wv][lane * 4] = v;
        __syncthreads();

        if (tid < 256) {
            // reduce 4 kq partials per gate; D idx: m'=b&15, n=g*4+du
            const int msub = bcell & 15;
            const int base_i = ((msub >> 2) * 16) * 4 + (msub & 3);
            float sg_[4];
            #pragma unroll
            for (int g = 0; g < 4; ++g) {
                int idx = base_i + (g * 4 + ducell) * 4;
                float sum = preW[0 * 4 + mtp][idx] + preW[1 * 4 + mtp][idx]
                          + preW[2 * 4 + mtp][idx] + preW[3 * 4 + mtp][idx];
                sg_[g] = sum;
            }
            float si = sg_[0] + bi_r, sf = sg_[1] + bf_r;
            float sg = sg_[2] + bg_r, so = sg_[3] + bo_r;
            float it = 1.f / (1.f + expf(-si));
            float ft = 1.f / (1.f + expf(-sf));
            float gt = tanhf(sg);
            float ot = 1.f / (1.f + expf(-so));
            float cn = ft * cReg + it * gt;
            cReg = cn;
            float hn = ot * tanhf(cn);
            f16* hFo = hF + (size_t)((s + 1) & 1) * 65536 + hfoOff;
            *hFo = (f16)hn;
            if (s == Sn - 1) {
                int gi = bcell * Hn + colcell;
                hOut[gi] = hn;
                cOut[gi] = cn;
            }
        }

        // ---- grid barrier (device-scope) ----
        __threadfence();          // release: hF stores visible device-wide
        __syncthreads();
        if (tid == 0) {
            atomicAdd(&barCnt[s], 1);
            while (__hip_atomic_load(&barCnt[s], __ATOMIC_ACQUIRE,
                                     __HIP_MEMORY_SCOPE_AGENT) < NBLK) {
                __builtin_amdgcn_s_sleep(1);
            }
        }
        __syncthreads();
        __threadfence();          // acquire: drop stale cached hF lines
    }
}

// ---- tail ----
__global__ __launch_bounds__(256) void copy_hc(
    const float* __restrict__ h, const float* __restrict__ c,
    float* __restrict__ out)
{
    int i = blockIdx.x * 256 + threadIdx.x;
    out[128 + i] = h[i];
    out[128 + Bn * Hn + i] = c[i];
}

__global__ __launch_bounds__(64) void classifier(
    const float* __restrict__ h, const float* __restrict__ Vw,
    const float* __restrict__ Vb, float* __restrict__ out)
{
    int bid = blockIdx.x;
    int b = bid >> 1, n = bid & 1;
    int lane = threadIdx.x;
    float sum = 0.f;
    for (int k = lane; k < Hn; k += 64)
        sum += h[b * Hn + k] * Vw[n * Hn + k];
    #pragma unroll
    for (int off = 32; off > 0; off >>= 1)
        sum += __shfl_down(sum, off, 64);
    if (lane == 0)
        out[b * 2 + n] = sum + Vb[n];
}

// ======================= fallback (round-1 proven path) =======================

#define KT 128
#define KTP 132

__global__ __launch_bounds__(256) void lstm_step_fb(
    const int* __restrict__ x, const float* __restrict__ emb,
    const float* __restrict__ Wxi, const float* __restrict__ Wxf,
    const float* __restrict__ Wxg, const float* __restrict__ Wxo,
    const float* __restrict__ bi, const float* __restrict__ bf,
    const float* __restrict__ bg, const float* __restrict__ bo,
    const float* __restrict__ Whi, const float* __restrict__ Whf,
    const float* __restrict__ Whg, const float* __restrict__ Who,
    const float* __restrict__ h_in, const float* __restrict__ c_in,
    float* __restrict__ h_out, float* __restrict__ c_out, int s)
{
    __shared__ float sh[Bn][KTP];
    __shared__ float sw[16][KTP];
    const int tid = threadIdx.x;
    const int b = tid >> 2, j = tid & 3;
    const int cb = blockIdx.x * 4, col = cb + j;
    float acc0 = 0.f, acc1 = 0.f, acc2 = 0.f, acc3 = 0.f;

    for (int k0 = 0; k0 < En; k0 += KT) {
        for (int i = tid; i < Bn * (KT / 4); i += 256) {
            int bl = i >> 5, k4 = (i & 31) << 2;
            int tok = x[bl * Sn + s];
            *reinterpret_cast<float4*>(&sh[bl][k4]) =
                *reinterpret_cast<const float4*>(&emb[(size_t)tok * En + k0 + k4]);
        }
        for (int i = tid; i < 16 * (KT / 4); i += 256) {
            int r = i >> 5, k4 = (i & 31) << 2;
            const float* Wg = (r < 8) ? ((r < 4) ? Wxi : Wxf)
                                      : ((r < 12) ? Wxg : Wxo);
            *reinterpret_cast<float4*>(&sw[r][k4]) =
                *reinterpret_cast<const float4*>(&Wg[(size_t)(cb + (r & 3)) * En + k0 + k4]);
        }
        __syncthreads();
        #pragma unroll 8
        for (int k = 0; k < KT; k += 4) {
            float4 hv = *reinterpret_cast<const float4*>(&sh[b][k]);
            float4 w0 = *reinterpret_cast<const float4*>(&sw[j][k]);
            float4 w1 = *reinterpret_cast<const float4*>(&sw[4 + j][k]);
            float4 w2 = *reinterpret_cast<const float4*>(&sw[8 + j][k]);
            float4 w3 = *reinterpret_cast<const float4*>(&sw[12 + j][k]);
            acc0 += hv.x*w0.x + hv.y*w0.y + hv.z*w0.z + hv.w*w0.w;
            acc1 += hv.x*w1.x + hv.y*w1.y + hv.z*w1.z + hv.w*w1.w;
            acc2 += hv.x*w2.x + hv.y*w2.y + hv.z*w2.z + hv.w*w2.w;
            acc3 += hv.x*w3.x + hv.y*w3.y + hv.z*w3.z + hv.w*w3.w;
        }
        __syncthreads();
    }
    for (int k0 = 0; k0 < Hn; k0 += KT) {
        for (int i = tid; i < Bn * (KT / 4); i += 256) {
            int bl = i >> 5, k4 = (i & 31) << 2;
            *reinterpret_cast<float4*>(&sh[bl][k4]) =
                *reinterpret_cast<const float4*>(&h_in[(size_t)bl * Hn + k0 + k4]);
        }
        for (int i = tid; i < 16 * (KT / 4); i += 256) {
            int r = i >> 5, k4 = (i & 31) << 2;
            const float* Wg = (r < 8) ? ((r < 4) ? Whi : Whf)
                                      : ((r < 12) ? Whg : Who);
            *reinterpret_cast<float4*>(&sw[r][k4]) =
                *reinterpret_cast<const float4*>(&Wg[(size_t)(cb + (r & 3)) * Hn + k0 + k4]);
        }
        __syncthreads();
        #pragma unroll 8
        for (int k = 0; k < KT; k += 4) {
            float4 hv = *reinterpret_cast<const float4*>(&sh[b][k]);
            float4 w0 = *reinterpret_cast<const float4*>(&sw[j][k]);
            float4 w1 = *reinterpret_cast<const float4*>(&sw[4 + j][k]);
            float4 w2 = *reinterpret_cast<const float4*>(&sw[8 + j][k]);
            float4 w3 = *reinterpret_cast<const float4*>(&sw[12 + j][k]);
            acc0 += hv.x*w0.x + hv.y*w0.y + hv.z*w0.z + hv.w*w0.w;
            acc1 += hv.x*w1.x + hv.y*w1.y + hv.z*w1.z + hv.w*w1.w;
            acc2 += hv.x*w2.x + hv.y*w2.y + hv.z*w2.z + hv.w*w2.w;
            acc3 += hv.x*w3.x + hv.y*w3.y + hv.z*w3.z + hv.w*w3.w;
        }
        __syncthreads();
    }
    acc0 += bi[col]; acc1 += bf[col]; acc2 += bg[col]; acc3 += bo[col];
    float it = 1.f / (1.f + expf(-acc0));
    float ft = 1.f / (1.f + expf(-acc1));
    float gt = tanhf(acc2);
    float ot = 1.f / (1.f + expf(-acc3));
    float cn = ft * c_in[b * Hn + col] + it * gt;
    c_out[b * Hn + col] = cn;
    h_out[b * Hn + col] = ot * tanhf(cn);
}

// ======================= launcher =======================

extern "C" void kernel_launch(void* const* d_in, const int* in_sizes, int n_in,
                              void* d_out, int out_size, void* d_ws, size_t ws_size,
                              hipStream_t stream) {
    const int*   x   = (const int*)  d_in[0];
    const float* emb = (const float*)d_in[1];
    const float* Wxi = (const float*)d_in[2];
    const float* bi  = (const float*)d_in[3];
    const float* Whi = (const float*)d_in[4];
    const float* Wxf = (const float*)d_in[5];
    const float* bf  = (const float*)d_in[6];
    const float* Whf = (const float*)d_in[7];
    const float* Wxg = (const float*)d_in[8];
    const float* bg  = (const float*)d_in[9];
    const float* Whg = (const float*)d_in[10];
    const float* Wxo = (const float*)d_in[11];
    const float* bo  = (const float*)d_in[12];
    const float* Who = (const float*)d_in[13];
    const float* Vw  = (const float*)d_in[14];
    const float* Vb  = (const float*)d_in[15];
    float* out = (float*)d_out;

    // ws layout: [hF 256K][barCnt 4K][c 256K][h 256K][eF 32M][wpHi 12M][wpLo 12M]
    const size_t szHF  = (size_t)2 * 65536 * sizeof(f16);             // 256 KB
    const size_t szBar = (size_t)1024 * sizeof(int);                  // 4 KB
    const size_t szC   = (size_t)Bn * Hn * sizeof(float);             // 256 KB
    const size_t szEF  = (size_t)Sn * 16 * 4 * 64 * 8 * sizeof(f16);  // 32 MB
    const size_t szWp  = (size_t)256 * 48 * 64 * 8 * sizeof(f16);     // 12 MB
    const size_t need  = szHF + szBar + 2 * szC + szEF + 2 * szWp;

    if (ws_size >= need) {
        char* base = (char*)d_ws;
        f16*   hF   = (f16*)base;   base += szHF;
        int*   bar  = (int*)base;   base += szBar;
        float* c    = (float*)base; base += szC;
        float* h    = (float*)base; base += szC;
        f16*   eF   = (f16*)base;   base += szEF;
        f16*   wpHi = (f16*)base;   base += szWp;
        f16*   wpLo = (f16*)base;

        // zero hF (both buffers) + barrier counters (adjacent at ws start)
        hipMemsetAsync(d_ws, 0, szHF + szBar, stream);
        wpack_kernel<<<dim3(3072), dim3(256), 0, stream>>>(
            Whi, Whf, Whg, Who, Wxi, Wxf, Wxg, Wxo, wpHi, wpLo);
        epack_kernel<<<dim3(8192), dim3(256), 0, stream>>>(x, emb, eF);

        lstm_persist<<<dim3(NBLK), dim3(1024), 0, stream>>>(
            hF, (const half8*)eF, (const half8*)wpHi, (const half8*)wpLo,
            bi, bf, bg, bo, h, c, bar);

        copy_hc<<<dim3(Bn * Hn / 256), dim3(256), 0, stream>>>(h, c, out);
        classifier<<<dim3(Bn * 2), dim3(64), 0, stream>>>(h, Vw, Vb, out);
    } else {
        float* hA = (float*)d_ws;
        float* cA = hA + Bn * Hn;
        float* hB = cA + Bn * Hn;
        float* cB = hB + Bn * Hn;
        hipMemsetAsync(d_ws, 0, (size_t)2 * Bn * Hn * sizeof(float), stream);
        for (int s = 0; s < Sn; ++s) {
            const float* hi = (s & 1) ? hB : hA;
            const float* ci = (s & 1) ? cB : cA;
            float* ho = (s & 1) ? hA : hB;
            float* co = (s & 1) ? cA : cB;
            lstm_step_fb<<<dim3(Hn / 4), dim3(256), 0, stream>>>(
                x, emb, Wxi, Wxf, Wxg, Wxo, bi, bf, bg, bo,
                Whi, Whf, Whg, Who, hi, ci, ho, co, s);
        }
        copy_hc<<<dim3(Bn * Hn / 256), dim3(256), 0, stream>>>(hA, cA, out);
        classifier<<<dim3(Bn * 2), dim3(64), 0, stream>>>(hA, Vw, Vb, out);
    }
}

// Round 6
// 4702.702 us; speedup vs baseline: 15.2588x; 15.2588x over previous
//
#include <hip/hip_runtime.h>
#include <math.h>

#define Bn 64
#define Hn 1024
#define En 512
#define Sn 512
#define RING 32

typedef _Float16 f16;
typedef _Float16 half8 __attribute__((ext_vector_type(8)));
typedef float f32x4 __attribute__((ext_vector_type(4)));

// ============================================================================
// Round 6: launch-per-step (proven) + 256-block step kernel + gx hoist.
//
// Fragment layouts (gfx950 mfma_f32_16x16x32_f16, HW-verified):
//   A[m][k]: m = lane&15, k = (lane>>4)*8 + j
//   B[k][n]: n = lane&15, k = (lane>>4)*8 + j
//   C/D[m][n]: n = lane&15, m = (lane>>4)*4 + reg
//
// hF (A-side f16, double buffer 64K halves each): [(kc*4+mt)*64+lane]*8+j =
//   h[b=mt*16+(lane&15)][k=kc*32+(lane>>4)*8+j], kc 0..31.
// eF (A-side f16): [s][(kcx*4+mt)*64+lane]*8+j, e-k 0..511 (kcx 0..15).
// wp (B-side f16, hi + lo*2048): [((bb*48+kc)*64+lane)*8+j] =
//   W_g[u=bb*4+du][k];  n=lane&15, g=n>>2, du=n&3;  bb 0..255.
//   kc<32: Wh_g @ k=kc*32+(lane>>4)*8+j;  kc>=32: Wx_g @ (kc-32)*32+...
// gx ring: [s%RING][b][col] f32, col = g*1024 + unit.
// ============================================================================

__global__ __launch_bounds__(256) void wpack_kernel(
    const float* __restrict__ Whi_, const float* __restrict__ Whf_,
    const float* __restrict__ Whg_, const float* __restrict__ Who_,
    const float* __restrict__ Wxi_, const float* __restrict__ Wxf_,
    const float* __restrict__ Wxg_, const float* __restrict__ Wxo_,
    f16* __restrict__ wpHi, f16* __restrict__ wpLo)
{
    int t = blockIdx.x * 256 + threadIdx.x;   // 786432 = 256*48*64
    int lane = t & 63;
    int rest = t >> 6;
    int kc = rest % 48;
    int bb = rest / 48;
    int n = lane & 15, g = n >> 2, du = n & 3;
    int u = bb * 4 + du;
    int klo = (lane >> 4) << 3;
    const float* Wh = (g == 0 ? Whi_ : g == 1 ? Whf_ : g == 2 ? Whg_ : Who_);
    const float* Wx = (g == 0 ? Wxi_ : g == 1 ? Wxf_ : g == 2 ? Wxg_ : Wxo_);
    const float* src = (kc < 32) ? (Wh + (size_t)u * Hn + kc * 32 + klo)
                                 : (Wx + (size_t)u * En + (kc - 32) * 32 + klo);
    float4 v0 = ((const float4*)src)[0];
    float4 v1 = ((const float4*)src)[1];
    float w[8] = {v0.x, v0.y, v0.z, v0.w, v1.x, v1.y, v1.z, v1.w};
    #pragma unroll
    for (int j = 0; j < 8; ++j) {
        f16 hi = (f16)w[j];
        float lo = (w[j] - (float)hi) * 2048.0f;
        wpHi[(size_t)t * 8 + j] = hi;
        wpLo[(size_t)t * 8 + j] = (f16)lo;
    }
}

__global__ __launch_bounds__(256) void epack_kernel(
    const int* __restrict__ x, const float* __restrict__ emb,
    f16* __restrict__ eF)
{
    int t = blockIdx.x * 256 + threadIdx.x;   // 2097152 = 512*16*4*64
    int lane = t & 63;
    int q = t >> 6;
    int mt = q & 3; q >>= 2;
    int kc2 = q & 15;
    int s = q >> 4;
    int b = mt * 16 + (lane & 15);
    int tok = x[b * Sn + s];
    int k = kc2 * 32 + ((lane >> 4) << 3);
    const float* src = emb + (size_t)tok * En + k;
    float4 v0 = ((const float4*)src)[0];
    float4 v1 = ((const float4*)src)[1];
    f16* dst = eF + (size_t)t * 8;
    dst[0] = (f16)v0.x; dst[1] = (f16)v0.y; dst[2] = (f16)v0.z; dst[3] = (f16)v0.w;
    dst[4] = (f16)v1.x; dst[5] = (f16)v1.y; dst[6] = (f16)v1.z; dst[7] = (f16)v1.w;
}

// gx for RING steps of one chunk, using wp's Wx part (kc 32..47).
// grid 2048 x 256 (4 waves): wave task = (sc, bb); 32*256 = 8192 tasks.
__global__ __launch_bounds__(256) void gx_chunk_kernel(
    const half8* __restrict__ eF,
    const half8* __restrict__ wpHi, const half8* __restrict__ wpLo,
    float* __restrict__ gx, int chunk)
{
    int lane = threadIdx.x & 63;
    int id = blockIdx.x * 4 + (threadIdx.x >> 6);
    int sc = id >> 8;            // 0..31
    int bb = id & 255;
    int s = chunk * RING + sc;

    const half8* eFs = eF + (size_t)s * 4096 + lane;
    const half8* bH = wpHi + ((size_t)(bb * 48 + 32)) * 64 + lane;
    const half8* bL = wpLo + ((size_t)(bb * 48 + 32)) * 64 + lane;

    f32x4 aH[4], aL[4];
    #pragma unroll
    for (int mt = 0; mt < 4; ++mt) { aH[mt] = (f32x4)0.0f; aL[mt] = (f32x4)0.0f; }

    for (int kcx = 0; kcx < 16; ++kcx) {
        half8 bh = bH[(size_t)kcx * 64];
        half8 bl = bL[(size_t)kcx * 64];
        #pragma unroll
        for (int mt = 0; mt < 4; ++mt) {
            half8 a = eFs[(size_t)((kcx * 4 + mt) * 64)];
            aH[mt] = __builtin_amdgcn_mfma_f32_16x16x32_f16(a, bh, aH[mt], 0, 0, 0);
            aL[mt] = __builtin_amdgcn_mfma_f32_16x16x32_f16(a, bl, aL[mt], 0, 0, 0);
        }
    }

    int n = lane & 15, g = n >> 2, du = n & 3;
    int col = (g << 10) + bb * 4 + du;
    float* g0 = gx + (size_t)sc * (Bn * 4096) + col;
    #pragma unroll
    for (int mt = 0; mt < 4; ++mt) {
        #pragma unroll
        for (int r = 0; r < 4; ++r) {
            int b = mt * 16 + ((lane >> 4) << 2) + r;
            g0[(size_t)b * 4096] = aH[mt][r] + aL[mt][r] * (1.0f / 2048.0f);
        }
    }
}

// Serial step: 256 blocks x 1024 thr. Block bb owns 16 cols (4 units x 4
// gates). Wave wv: mt = wv&3, kq = wv>>2. Cross-kq reduce via LDS + cell.
template<bool USE_GX>
__global__ __launch_bounds__(1024) void step_kernel(
    const f16* __restrict__ hFin, f16* __restrict__ hFout,
    const half8* __restrict__ eF,
    const half8* __restrict__ wpHi, const half8* __restrict__ wpLo,
    const float* __restrict__ gx,
    const float* __restrict__ bi, const float* __restrict__ bf,
    const float* __restrict__ bg, const float* __restrict__ bo,
    float* __restrict__ c, float* __restrict__ hFinal, int s)
{
    __shared__ float preW[16][256];       // 16 KB

    const int tid  = threadIdx.x;
    const int lane = tid & 63;
    const int wv   = tid >> 6;
    const int mt   = wv & 3;
    const int kq   = wv >> 2;
    const int bb   = blockIdx.x;

    const half8* hin = (const half8*)hFin + lane;
    const half8* bHb = wpHi + (size_t)(bb * 48) * 64 + lane;
    const half8* bLb = wpLo + (size_t)(bb * 48) * 64 + lane;

    f32x4 accH = {0.f, 0.f, 0.f, 0.f};
    f32x4 accL = {0.f, 0.f, 0.f, 0.f};

    if (USE_GX) {
        #pragma unroll
        for (int i = 0; i < 8; ++i) {
            int kc = kq * 8 + i;
            half8 a  = hin[(size_t)((kc * 4 + mt) * 64)];
            half8 bh = bHb[(size_t)kc * 64];
            half8 bl = bLb[(size_t)kc * 64];
            accH = __builtin_amdgcn_mfma_f32_16x16x32_f16(a, bh, accH, 0, 0, 0);
            accL = __builtin_amdgcn_mfma_f32_16x16x32_f16(a, bl, accL, 0, 0, 0);
        }
    } else {
        const half8* eFs = eF + (size_t)s * 4096 + lane;
        #pragma unroll
        for (int i = 0; i < 12; ++i) {
            int kc = kq * 12 + i;
            half8 a = (kc < 32) ? hin[(size_t)((kc * 4 + mt) * 64)]
                                : eFs[(size_t)(((kc - 32) * 4 + mt) * 64)];
            half8 bh = bHb[(size_t)kc * 64];
            half8 bl = bLb[(size_t)kc * 64];
            accH = __builtin_amdgcn_mfma_f32_16x16x32_f16(a, bh, accH, 0, 0, 0);
            accL = __builtin_amdgcn_mfma_f32_16x16x32_f16(a, bl, accL, 0, 0, 0);
        }
    }

    f32x4 v;
    #pragma unroll
    for (int r = 0; r < 4; ++r) v[r] = accH[r] + accL[r] * (1.0f / 2048.0f);
    *(f32x4*)&preW[wv][lane * 4] = v;
    __syncthreads();

    if (tid < 256) {
        const int bcell = tid >> 2, ducell = tid & 3;
        const int colcell = bb * 4 + ducell;          // h-unit 0..1023
        const int msub = bcell & 15, mtp = bcell >> 4;
        const int base_i = ((msub >> 2) * 16) * 4 + (msub & 3);
        float sg_[4];
        #pragma unroll
        for (int g = 0; g < 4; ++g) {
            int idx = base_i + (g * 4 + ducell) * 4;
            sg_[g] = preW[0 * 4 + mtp][idx] + preW[1 * 4 + mtp][idx]
                   + preW[2 * 4 + mtp][idx] + preW[3 * 4 + mtp][idx];
        }
        float si = sg_[0] + bi[colcell];
        float sf = sg_[1] + bf[colcell];
        float sg = sg_[2] + bg[colcell];
        float so = sg_[3] + bo[colcell];
        if (USE_GX) {
            const float* gr = gx + ((size_t)(s & (RING - 1)) * Bn + bcell) * 4096;
            si += gr[colcell];        sf += gr[1024 + colcell];
            sg += gr[2048 + colcell]; so += gr[3072 + colcell];
        }
        float it = 1.f / (1.f + expf(-si));
        float ft = 1.f / (1.f + expf(-sf));
        float gt = tanhf(sg);
        float ot = 1.f / (1.f + expf(-so));
        int gi = bcell * Hn + colcell;
        float cn = ft * c[gi] + it * gt;
        c[gi] = cn;
        float hn = ot * tanhf(cn);
        // scatter into next step's A-frag layout
        int kch = colcell >> 5, dk = colcell & 31;
        int lp  = ((dk >> 3) << 4) | (bcell & 15);
        int mtp2 = bcell >> 4;
        hFout[((size_t)((kch * 4 + mtp2) * 64 + lp)) * 8 + (dk & 7)] = (f16)hn;
        if (s == Sn - 1) hFinal[gi] = hn;
    }
}

// ---- tail ----
__global__ __launch_bounds__(256) void copy_hc(
    const float* __restrict__ h, const float* __restrict__ c,
    float* __restrict__ out)
{
    int i = blockIdx.x * 256 + threadIdx.x;
    out[128 + i] = h[i];
    out[128 + Bn * Hn + i] = c[i];
}

__global__ __launch_bounds__(64) void classifier(
    const float* __restrict__ h, const float* __restrict__ Vw,
    const float* __restrict__ Vb, float* __restrict__ out)
{
    int bid = blockIdx.x;
    int b = bid >> 1, n = bid & 1;
    int lane = threadIdx.x;
    float sum = 0.f;
    for (int k = lane; k < Hn; k += 64)
        sum += h[b * Hn + k] * Vw[n * Hn + k];
    #pragma unroll
    for (int off = 32; off > 0; off >>= 1)
        sum += __shfl_down(sum, off, 64);
    if (lane == 0)
        out[b * 2 + n] = sum + Vb[n];
}

// ======================= fallback (round-1 proven path) =======================

#define KT 128
#define KTP 132

__global__ __launch_bounds__(256) void lstm_step_fb(
    const int* __restrict__ x, const float* __restrict__ emb,
    const float* __restrict__ Wxi, const float* __restrict__ Wxf,
    const float* __restrict__ Wxg, const float* __restrict__ Wxo,
    const float* __restrict__ bi, const float* __restrict__ bf,
    const float* __restrict__ bg, const float* __restrict__ bo,
    const float* __restrict__ Whi, const float* __restrict__ Whf,
    const float* __restrict__ Whg, const float* __restrict__ Who,
    const float* __restrict__ h_in, const float* __restrict__ c_in,
    float* __restrict__ h_out, float* __restrict__ c_out, int s)
{
    __shared__ float sh[Bn][KTP];
    __shared__ float sw[16][KTP];
    const int tid = threadIdx.x;
    const int b = tid >> 2, j = tid & 3;
    const int cb = blockIdx.x * 4, col = cb + j;
    float acc0 = 0.f, acc1 = 0.f, acc2 = 0.f, acc3 = 0.f;

    for (int k0 = 0; k0 < En; k0 += KT) {
        for (int i = tid; i < Bn * (KT / 4); i += 256) {
            int bl = i >> 5, k4 = (i & 31) << 2;
            int tok = x[bl * Sn + s];
            *reinterpret_cast<float4*>(&sh[bl][k4]) =
                *reinterpret_cast<const float4*>(&emb[(size_t)tok * En + k0 + k4]);
        }
        for (int i = tid; i < 16 * (KT / 4); i += 256) {
            int r = i >> 5, k4 = (i & 31) << 2;
            const float* Wg = (r < 8) ? ((r < 4) ? Wxi : Wxf)
                                      : ((r < 12) ? Wxg : Wxo);
            *reinterpret_cast<float4*>(&sw[r][k4]) =
                *reinterpret_cast<const float4*>(&Wg[(size_t)(cb + (r & 3)) * En + k0 + k4]);
        }
        __syncthreads();
        #pragma unroll 8
        for (int k = 0; k < KT; k += 4) {
            float4 hv = *reinterpret_cast<const float4*>(&sh[b][k]);
            float4 w0 = *reinterpret_cast<const float4*>(&sw[j][k]);
            float4 w1 = *reinterpret_cast<const float4*>(&sw[4 + j][k]);
            float4 w2 = *reinterpret_cast<const float4*>(&sw[8 + j][k]);
            float4 w3 = *reinterpret_cast<const float4*>(&sw[12 + j][k]);
            acc0 += hv.x*w0.x + hv.y*w0.y + hv.z*w0.z + hv.w*w0.w;
            acc1 += hv.x*w1.x + hv.y*w1.y + hv.z*w1.z + hv.w*w1.w;
            acc2 += hv.x*w2.x + hv.y*w2.y + hv.z*w2.z + hv.w*w2.w;
            acc3 += hv.x*w3.x + hv.y*w3.y + hv.z*w3.z + hv.w*w3.w;
        }
        __syncthreads();
    }
    for (int k0 = 0; k0 < Hn; k0 += KT) {
        for (int i = tid; i < Bn * (KT / 4); i += 256) {
            int bl = i >> 5, k4 = (i & 31) << 2;
            *reinterpret_cast<float4*>(&sh[bl][k4]) =
                *reinterpret_cast<const float4*>(&h_in[(size_t)bl * Hn + k0 + k4]);
        }
        for (int i = tid; i < 16 * (KT / 4); i += 256) {
            int r = i >> 5, k4 = (i & 31) << 2;
            const float* Wg = (r < 8) ? ((r < 4) ? Whi : Whf)
                                      : ((r < 12) ? Whg : Who);
            *reinterpret_cast<float4*>(&sw[r][k4]) =
                *reinterpret_cast<const float4*>(&Wg[(size_t)(cb + (r & 3)) * Hn + k0 + k4]);
        }
        __syncthreads();
        #pragma unroll 8
        for (int k = 0; k < KT; k += 4) {
            float4 hv = *reinterpret_cast<const float4*>(&sh[b][k]);
            float4 w0 = *reinterpret_cast<const float4*>(&sw[j][k]);
            float4 w1 = *reinterpret_cast<const float4*>(&sw[4 + j][k]);
            float4 w2 = *reinterpret_cast<const float4*>(&sw[8 + j][k]);
            float4 w3 = *reinterpret_cast<const float4*>(&sw[12 + j][k]);
            acc0 += hv.x*w0.x + hv.y*w0.y + hv.z*w0.z + hv.w*w0.w;
            acc1 += hv.x*w1.x + hv.y*w1.y + hv.z*w1.z + hv.w*w1.w;
            acc2 += hv.x*w2.x + hv.y*w2.y + hv.z*w2.z + hv.w*w2.w;
            acc3 += hv.x*w3.x + hv.y*w3.y + hv.z*w3.z + hv.w*w3.w;
        }
        __syncthreads();
    }
    acc0 += bi[col]; acc1 += bf[col]; acc2 += bg[col]; acc3 += bo[col];
    float it = 1.f / (1.f + expf(-acc0));
    float ft = 1.f / (1.f + expf(-acc1));
    float gt = tanhf(acc2);
    float ot = 1.f / (1.f + expf(-acc3));
    float cn = ft * c_in[b * Hn + col] + it * gt;
    c_out[b * Hn + col] = cn;
    h_out[b * Hn + col] = ot * tanhf(cn);
}

// ======================= launcher =======================

extern "C" void kernel_launch(void* const* d_in, const int* in_sizes, int n_in,
                              void* d_out, int out_size, void* d_ws, size_t ws_size,
                              hipStream_t stream) {
    const int*   x   = (const int*)  d_in[0];
    const float* emb = (const float*)d_in[1];
    const float* Wxi = (const float*)d_in[2];
    const float* bi  = (const float*)d_in[3];
    const float* Whi = (const float*)d_in[4];
    const float* Wxf = (const float*)d_in[5];
    const float* bf  = (const float*)d_in[6];
    const float* Whf = (const float*)d_in[7];
    const float* Wxg = (const float*)d_in[8];
    const float* bg  = (const float*)d_in[9];
    const float* Whg = (const float*)d_in[10];
    const float* Wxo = (const float*)d_in[11];
    const float* bo  = (const float*)d_in[12];
    const float* Who = (const float*)d_in[13];
    const float* Vw  = (const float*)d_in[14];
    const float* Vb  = (const float*)d_in[15];
    float* out = (float*)d_out;

    // ws: [hF 256K][c 256K][h 256K][eF 32M][wpHi 12M][wpLo 12M][gx 32M]
    const size_t szHF = (size_t)2 * 65536 * sizeof(f16);              // 256 KB
    const size_t szC  = (size_t)Bn * Hn * sizeof(float);              // 256 KB
    const size_t szEF = (size_t)Sn * 16 * 4 * 64 * 8 * sizeof(f16);   // 32 MB
    const size_t szWp = (size_t)256 * 48 * 64 * 8 * sizeof(f16);      // 12 MB
    const size_t szGx = (size_t)RING * Bn * 4096 * sizeof(float);     // 32 MB
    const size_t need_mid = szHF + 2 * szC + szEF + 2 * szWp;
    const size_t need_gx  = need_mid + szGx;

    if (ws_size >= need_mid) {
        const bool useGx = (ws_size >= need_gx);
        char* base = (char*)d_ws;
        f16*   hF   = (f16*)base;   base += szHF;
        float* c    = (float*)base; base += szC;
        float* h    = (float*)base; base += szC;
        f16*   eF   = (f16*)base;   base += szEF;
        f16*   wpHi = (f16*)base;   base += szWp;
        f16*   wpLo = (f16*)base;   base += szWp;
        float* gx   = (float*)base;

        hipMemsetAsync(d_ws, 0, szHF + szC, stream);   // hF both bufs + c
        wpack_kernel<<<dim3(3072), dim3(256), 0, stream>>>(
            Whi, Whf, Whg, Who, Wxi, Wxf, Wxg, Wxo, wpHi, wpLo);
        epack_kernel<<<dim3(8192), dim3(256), 0, stream>>>(x, emb, eF);

        if (useGx) {
            for (int chunk = 0; chunk < Sn / RING; ++chunk) {
                gx_chunk_kernel<<<dim3(2048), dim3(256), 0, stream>>>(
                    (const half8*)eF, (const half8*)wpHi, (const half8*)wpLo,
                    gx, chunk);
                for (int sc = 0; sc < RING; ++sc) {
                    int s = chunk * RING + sc;
                    const f16* hin  = hF + (size_t)(s & 1) * 65536;
                    f16*       hout = hF + (size_t)((s + 1) & 1) * 65536;
                    step_kernel<true><<<dim3(256), dim3(1024), 0, stream>>>(
                        hin, hout, (const half8*)eF,
                        (const half8*)wpHi, (const half8*)wpLo,
                        gx, bi, bf, bg, bo, c, h, s);
                }
            }
        } else {
            for (int s = 0; s < Sn; ++s) {
                const f16* hin  = hF + (size_t)(s & 1) * 65536;
                f16*       hout = hF + (size_t)((s + 1) & 1) * 65536;
                step_kernel<false><<<dim3(256), dim3(1024), 0, stream>>>(
                    hin, hout, (const half8*)eF,
                    (const half8*)wpHi, (const half8*)wpLo,
                    (const float*)nullptr, bi, bf, bg, bo, c, h, s);
            }
        }
        copy_hc<<<dim3(Bn * Hn / 256), dim3(256), 0, stream>>>(h, c, out);
        classifier<<<dim3(Bn * 2), dim3(64), 0, stream>>>(h, Vw, Vb, out);
    } else {
        float* hA = (float*)d_ws;
        float* cA = hA + Bn * Hn;
        float* hB = cA + Bn * Hn;
        float* cB = hB + Bn * Hn;
        hipMemsetAsync(d_ws, 0, (size_t)2 * Bn * Hn * sizeof(float), stream);
        for (int s = 0; s < Sn; ++s) {
            const float* hi = (s & 1) ? hB : hA;
            const float* ci = (s & 1) ? cB : cA;
            float* ho = (s & 1) ? hA : hB;
            float* co = (s & 1) ? cA : cB;
            lstm_step_fb<<<dim3(Hn / 4), dim3(256), 0, stream>>>(
                x, emb, Wxi, Wxf, Wxg, Wxo, bi, bf, bg, bo,
                Whi, Whf, Whg, Who, hi, ci, ho, co, s);
        }
        copy_hc<<<dim3(Bn * Hn / 256), dim3(256), 0, stream>>>(hA, cA, out);
        classifier<<<dim3(Bn * 2), dim3(64), 0, stream>>>(hA, Vw, Vb, out);
    }
}